// Round 5
// baseline (697.595 us; speedup 1.0000x reference)
//
#include <hip/hip_runtime.h>
#include <hip/hip_bf16.h>

#define IN_CH   2048
#define OUT_CH  256
#define GROUPS  32
#define CPG     8        // channels per group
#define BATCH   16
#define HW      4096     // 64*64
#define EPS     1e-5f
#define NBLK    512
#define RPB     4        // rows per block per batch (1 per wave)

typedef float f32x4 __attribute__((ext_vector_type(4)));

// ---------------------------------------------------------------------------
// Single persistent kernel, 512 blocks x 256 threads, all co-resident
// (__launch_bounds__(256,2) -> VGPR<=256 -> >=2 blocks/CU -> 512 fit).
//
// Per batch b: each block pools its 4 rows (wave-per-row, 16 NT float4 loads
// in flight), then release-publishes pool_done[b].  One batch later it emits
// batch b-1: acquire-spin on pool_done, stage pooled row in LDS, recompute its
// group's 8 dot products (W stays L2-hot; no second sync level needed),
// GroupNorm+ReLU, NT-store its 8 KB slice of the broadcast output.
// Writes of batch b-1 overlap pool reads of batches b..15; no launch gap.
// ---------------------------------------------------------------------------
__global__ __launch_bounds__(256, 2) void fused_kernel(
        const float* __restrict__ x,
        const float* __restrict__ W,
        const float* __restrict__ gamma,
        const float* __restrict__ beta,
        float* __restrict__ pooled,
        int* __restrict__ pool_done,
        f32x4* __restrict__ out) {
    const int j    = blockIdx.x;     // 0..511
    const int t    = threadIdx.x;    // 0..255
    const int w    = t >> 6;         // wave 0..3
    const int lane = t & 63;

    const int o  = j >> 1;           // output channel this block broadcasts
    const int g  = o >> 3;           // its group
    const int ch = t >> 5;           // channel-in-group for gn compute (0..7)
    const int i  = t & 31;           // lane within channel (0..31)

    const float gam = gamma[o];
    const float bet = beta[o];

    __shared__ float p[IN_CH];       // staged pooled row (8 KB)
    __shared__ float hsh[CPG];

    auto emit = [&](int bb) {
        // wait for batch bb's pool to be fully published
        if (t == 0) {
            while (__hip_atomic_load(&pool_done[bb], __ATOMIC_ACQUIRE,
                                     __HIP_MEMORY_SCOPE_AGENT) < IN_CH)
                __builtin_amdgcn_s_sleep(2);
        }
        __syncthreads();

        // stage pooled[bb] row into LDS
        const float4* pg  = reinterpret_cast<const float4*>(pooled + (size_t)bb * IN_CH);
        float4*       p4s = reinterpret_cast<float4*>(p);
        p4s[t]       = pg[t];
        p4s[t + 256] = pg[t + 256];
        __syncthreads();

        // 8 dot products for group g (thread = (ch, i))
        const float4* wr = reinterpret_cast<const float4*>(W + (size_t)(g * CPG + ch) * IN_CH);
        const float4* p4 = reinterpret_cast<const float4*>(p);
        float acc = 0.0f;
#pragma unroll
        for (int k = 0; k < IN_CH / 4 / 32; ++k) {   // 16 iters
            float4 wv = wr[i + 32 * k];
            float4 pv = p4[i + 32 * k];
            acc += pv.x * wv.x + pv.y * wv.y + pv.z * wv.z + pv.w * wv.w;
        }
#pragma unroll
        for (int m = 1; m < 32; m <<= 1) acc += __shfl_xor(acc, m, 64);
        if (i == 0) hsh[ch] = acc;
        __syncthreads();

        float sum = 0.0f, sumsq = 0.0f;
#pragma unroll
        for (int c = 0; c < CPG; ++c) { float h = hsh[c]; sum += h; sumsq += h * h; }
        const float mu  = sum * (1.0f / (float)CPG);
        const float var = sumsq * (1.0f / (float)CPG) - mu * mu;
        const float r   = rsqrtf(var + EPS);
        const float v   = fmaxf((hsh[o & 7] - mu) * r * gam + bet, 0.0f);

        // write this block's 512 float4 (8 KB) of channel o's plane
        f32x4 v4 = {v, v, v, v};
        f32x4* outp = out + (size_t)bb * (OUT_CH * HW / 4) + (size_t)j * 512;
        __builtin_nontemporal_store(v4, outp + t);
        __builtin_nontemporal_store(v4, outp + t + 256);
    };

    for (int b = 0; b < BATCH; ++b) {
        // ---- pool this block's 4 rows of batch b (wave-per-row) ----
        {
            const int row = b * IN_CH + j * RPB + w;
            const f32x4* xr = reinterpret_cast<const f32x4*>(x + (size_t)row * HW);
            f32x4 a[16];
#pragma unroll
            for (int k = 0; k < 16; ++k)
                a[k] = __builtin_nontemporal_load(xr + lane + 64 * k);
            float s = 0.0f;
#pragma unroll
            for (int k = 0; k < 16; ++k)
                s += (a[k].x + a[k].y) + (a[k].z + a[k].w);
#pragma unroll
            for (int off = 32; off > 0; off >>= 1) s += __shfl_down(s, off, 64);
            if (lane == 0) pooled[row] = s * (1.0f / (float)HW);
        }
        __syncthreads();   // all 4 rows of this block written
        if (t == 0)
            __hip_atomic_fetch_add(&pool_done[b], RPB, __ATOMIC_RELEASE,
                                   __HIP_MEMORY_SCOPE_AGENT);

        if (b >= 1) emit(b - 1);   // overlap batch b-1 output with later pools
    }
    emit(BATCH - 1);
}

extern "C" void kernel_launch(void* const* d_in, const int* in_sizes, int n_in,
                              void* d_out, int out_size, void* d_ws, size_t ws_size,
                              hipStream_t stream) {
    const float* x     = (const float*)d_in[0];
    const float* W     = (const float*)d_in[1];
    const float* gamma = (const float*)d_in[2];
    const float* beta  = (const float*)d_in[3];

    float* pooled    = (float*)d_ws;                       // 32768 floats = 128 KiB
    int*   pool_done = (int*)((char*)d_ws + BATCH * IN_CH * sizeof(float));  // 16 ints

    hipMemsetAsync(pool_done, 0, BATCH * sizeof(int), stream);
    fused_kernel<<<NBLK, 256, 0, stream>>>(x, W, gamma, beta, pooled, pool_done,
                                           (f32x4*)d_out);
}

// Round 6
// 100.877 us; speedup vs baseline: 6.9153x; 6.9153x over previous
//
#include <hip/hip_runtime.h>
#include <hip/hip_bf16.h>

#define IN_CH   2048
#define OUT_CH  256
#define GROUPS  32
#define CPG     (OUT_CH / GROUPS)   // 8 channels per group
#define BATCH   16
#define HW      4096                // 64*64
#define EPS     1e-5f

typedef float f32x4 __attribute__((ext_vector_type(4)));

// ---------------------------------------------------------------------------
// Kernel 1: global average pool.  One WAVE per (b,c) row of 4096 floats.
// Each lane issues 16 nontemporal float4 loads (16 KB/row, all in flight),
// accumulates in registers, 6-step shuffle butterfly, lane 0 stores.
// No LDS, no __syncthreads, no idle tail threads.
// 8192 blocks x 4 waves = 32768 rows.  Runs at ~6.3 TB/s (streaming-read
// ceiling, m13).
// ---------------------------------------------------------------------------
__global__ __launch_bounds__(256) void pool_kernel(const float* __restrict__ x,
                                                   float* __restrict__ pooled) {
    const int w    = threadIdx.x >> 6;
    const int lane = threadIdx.x & 63;
    const int row  = blockIdx.x * 4 + w;  // b*IN_CH + c
    const f32x4* xr = reinterpret_cast<const f32x4*>(x + (size_t)row * HW);

    f32x4 a[16];
#pragma unroll
    for (int k = 0; k < 16; ++k)
        a[k] = __builtin_nontemporal_load(xr + lane + 64 * k);

    float s = 0.0f;
#pragma unroll
    for (int k = 0; k < 16; ++k)
        s += (a[k].x + a[k].y) + (a[k].z + a[k].w);

#pragma unroll
    for (int off = 32; off > 0; off >>= 1) s += __shfl_down(s, off, 64);

    if (lane == 0) pooled[row] = s * (1.0f / (float)HW);
}

// ---------------------------------------------------------------------------
// Kernel 2 (fused): matmul + GroupNorm + ReLU + broadcast-write.
// One block per (batch, group): 16*32 = 512 blocks, 256 threads.
// Channel layout: ch = t>>5 (8 channels), i = t&31 (32 threads per channel).
// ---------------------------------------------------------------------------
__global__ __launch_bounds__(256) void gn_bcast_kernel(const float* __restrict__ pooled,
                                                       const float* __restrict__ W,
                                                       const float* __restrict__ gamma,
                                                       const float* __restrict__ beta,
                                                       f32x4* __restrict__ out) {
    const int b = blockIdx.x >> 5;       // 0..15
    const int g = blockIdx.x & 31;       // 0..31
    const int t = threadIdx.x;
    const int ch = t >> 5;               // 0..7  (channel within group)
    const int i  = t & 31;               // 0..31 (thread within channel)
    const int o  = g * CPG + ch;         // out-channel 0..255

    // stage pooled row [2048] in LDS
    __shared__ float p[IN_CH];
    for (int c = t; c < IN_CH; c += 256) p[c] = pooled[b * IN_CH + c];
    __syncthreads();

    // dot product: thread i covers float4 indices {i, i+32, ..., i+480}
    const float4* wr = reinterpret_cast<const float4*>(W + (size_t)o * IN_CH);
    const float4* p4 = reinterpret_cast<const float4*>(p);
    float acc = 0.0f;
#pragma unroll
    for (int k = 0; k < IN_CH / 4 / 32; ++k) {   // 16 iters
        float4 w  = wr[i + 32 * k];
        float4 pv = p4[i + 32 * k];
        acc += pv.x * w.x + pv.y * w.y + pv.z * w.z + pv.w * w.w;
    }
    // 32-lane butterfly (stays within the channel's half-wave)
#pragma unroll
    for (int m = 1; m < 32; m <<= 1) acc += __shfl_xor(acc, m, 64);
    // now every lane of the channel holds h[b,o] = acc

    // group statistics across the 8 channels (cross-wave -> LDS)
    __shared__ float hsh[CPG];
    if (i == 0) hsh[ch] = acc;
    __syncthreads();
    float sum = 0.0f, sumsq = 0.0f;
#pragma unroll
    for (int c = 0; c < CPG; ++c) {
        float h = hsh[c];
        sum += h;
        sumsq += h * h;
    }
    const float mu  = sum * (1.0f / (float)CPG);
    const float var = sumsq * (1.0f / (float)CPG) - mu * mu;
    const float r   = rsqrtf(var + EPS);

    float v = fmaxf((acc - mu) * r * gamma[o] + beta[o], 0.0f);

    // broadcast-write this channel's 64x64 plane: 1024 float4, 32 per thread
    // nontemporal: write-once stream, keep out of L2
    f32x4* outp = out + (size_t)(b * OUT_CH + o) * (HW / 4);
    const f32x4 v4 = {v, v, v, v};
#pragma unroll
    for (int k = 0; k < HW / 4 / 32; ++k) {      // 32 iters
        __builtin_nontemporal_store(v4, outp + i + 32 * k);
    }
}

extern "C" void kernel_launch(void* const* d_in, const int* in_sizes, int n_in,
                              void* d_out, int out_size, void* d_ws, size_t ws_size,
                              hipStream_t stream) {
    const float* x     = (const float*)d_in[0];
    const float* W     = (const float*)d_in[1];
    const float* gamma = (const float*)d_in[2];
    const float* beta  = (const float*)d_in[3];

    float* pooled = (float*)d_ws;                   // 16*2048 floats = 128 KiB

    pool_kernel<<<BATCH * IN_CH / 4, 256, 0, stream>>>(x, pooled);
    gn_bcast_kernel<<<BATCH * GROUPS, 256, 0, stream>>>(pooled, W, gamma, beta,
                                                        (f32x4*)d_out);
}